// Round 1
// baseline (208.177 us; speedup 1.0000x reference)
//
#include <hip/hip_runtime.h>
#include <math.h>

// Problem constants (from reference)
#define TAU 32.0f
constexpr int INDIM = 768;
constexpr int E     = 256;
constexpr int D     = 9;
constexpr int M     = 10;
constexpr int DM    = 90;    // D*M
constexpr int NC    = 180;   // 2*DM (P rows then R rows)
constexpr int NCP   = 192;   // padded column count
constexpr int BM    = 32;    // rows per block
constexpr int BK    = 32;    // k-tile

// ---------------------------------------------------------------------------
// Kernel 1: PR[blk][i] for blk in [0,180): contraction of memory row with W.
//   blk in [0,90):   P[dm][i] = sum_e memory[dm][e] * W_topic[e][i]
//   blk in [90,180): R[dm][i] = sum_e memory[dm][e] * W_domain[e][i]
//   blk in [180,192): zero padding rows
// grid 192, block 256
// ---------------------------------------------------------------------------
__global__ __launch_bounds__(256) void precompute_pr(
    const float* __restrict__ Wt, const float* __restrict__ Wd,
    const float* __restrict__ mem, float* __restrict__ PR) {
  int blk = blockIdx.x;
  int t   = threadIdx.x;
  if (blk >= NC) {
    for (int p = 0; p < 3; ++p) PR[(size_t)blk * INDIM + t + p * 256] = 0.0f;
    return;
  }
  __shared__ float mlds[E];
  int sel = blk / DM;
  int dm  = blk % DM;
  const float* W = sel ? Wd : Wt;
  mlds[t] = mem[(size_t)dm * E + t];   // t < 256 == E
  __syncthreads();
  #pragma unroll 3
  for (int p = 0; p < 3; ++p) {
    int i = t + p * 256;
    float acc = 0.0f;
    #pragma unroll 8
    for (int e = 0; e < E; ++e) acc += mlds[e] * W[(size_t)e * INDIM + i];
    PR[(size_t)blk * INDIM + i] = acc;
  }
}

// ---------------------------------------------------------------------------
// Kernel 2: fused GEMM [B,768]x[768,192] + row L2-norm + double softmax.
// Block: 256 threads, BM=32 rows, all 192 (180 live) columns, K=768.
// Thread (tx=t&31, ty=t>>5) computes rows ty*4..+3 x cols tx*6..+5.
// ---------------------------------------------------------------------------
__global__ __launch_bounds__(256) void fused_kernel(
    const float* __restrict__ feat, const float* __restrict__ PR,
    float* __restrict__ out) {
  __shared__ float Al[BK][BM + 4];    // 32x36, +4 keeps float4 reads 16B-aligned
  __shared__ float Bl[BK][NCP + 1];   // 32x193, odd stride -> conflict-free writes
  __shared__ float inv_l[BM];
  __shared__ float s_arr[BM * D];

  const int t  = threadIdx.x;
  const int tx = t & 31;
  const int ty = t >> 5;
  const int b0 = blockIdx.x * BM;

  float acc[4][6];
  #pragma unroll
  for (int i = 0; i < 4; ++i)
    #pragma unroll
    for (int j = 0; j < 6; ++j) acc[i][j] = 0.0f;
  float ssq[4] = {0.f, 0.f, 0.f, 0.f};

  for (int kt = 0; kt < INDIM / BK; ++kt) {
    const int k0 = kt * BK;
    // stage A: thread handles rows (i*8+ty), k = tx  (coalesced in tx)
    float av[4];
    #pragma unroll
    for (int i = 0; i < 4; ++i) {
      int row = i * 8 + ty;
      av[i] = feat[(size_t)(b0 + row) * INDIM + k0 + tx];
    }
    // stage B: thread handles cols (i*8+ty), k = tx  (coalesced in tx)
    float bv[24];
    #pragma unroll
    for (int i = 0; i < 24; ++i) {
      int col = i * 8 + ty;
      bv[i] = PR[(size_t)col * INDIM + k0 + tx];
    }
    __syncthreads();  // previous tile's compute done before overwrite
    #pragma unroll
    for (int i = 0; i < 4; ++i) {
      Al[tx][i * 8 + ty] = av[i];
      ssq[i] += av[i] * av[i];
    }
    #pragma unroll
    for (int i = 0; i < 24; ++i) Bl[tx][i * 8 + ty] = bv[i];
    __syncthreads();
    #pragma unroll
    for (int k = 0; k < BK; ++k) {
      float4 a4 = *(const float4*)&Al[k][ty * 4];
      const float* ap = (const float*)&a4;
      float bb[6];
      #pragma unroll
      for (int j = 0; j < 6; ++j) bb[j] = Bl[k][tx * 6 + j];
      #pragma unroll
      for (int ii = 0; ii < 4; ++ii)
        #pragma unroll
        for (int j = 0; j < 6; ++j) acc[ii][j] += ap[ii] * bb[j];
    }
  }

  __syncthreads();  // done reading Bl; about to reuse it for C

  // reduce ssq across the 32 tx lanes (same ty); masks <32 stay in half-wave
  #pragma unroll
  for (int i = 0; i < 4; ++i) {
    float v = ssq[i];
    #pragma unroll
    for (int mdel = 16; mdel >= 1; mdel >>= 1) v += __shfl_xor(v, mdel, 64);
    if (tx == 0) inv_l[i * 8 + ty] = rsqrtf(v);
  }
  __syncthreads();

  // C (=q|r, scaled by invnorm) into Bl as [row][col]
  #pragma unroll
  for (int ii = 0; ii < 4; ++ii) {
    float inv = inv_l[ty * 4 + ii];
    #pragma unroll
    for (int j = 0; j < 6; ++j) Bl[ty * 4 + ii][tx * 6 + j] = acc[ii][j] * inv;
  }
  __syncthreads();

  // phase C part 1: per (row,d): softmax over m of TAU*q, dot with r
  for (int pid = t; pid < BM * D; pid += 256) {
    int row = pid / D, d = pid % D;
    float q[M], r[M];
    #pragma unroll
    for (int m = 0; m < M; ++m) {
      q[m] = Bl[row][d * M + m];
      r[m] = Bl[row][DM + d * M + m];
    }
    float mx = q[0];
    #pragma unroll
    for (int m = 1; m < M; ++m) mx = fmaxf(mx, q[m]);
    float s = 0.f, val = 0.f;
    #pragma unroll
    for (int m = 0; m < M; ++m) {
      float e = __expf(TAU * (q[m] - mx));
      s += e;
      val += e * r[m];
    }
    s_arr[row * D + d] = val / s;
  }
  __syncthreads();

  // phase C part 2: per row softmax over d, write output
  if (t < BM) {
    int row = t;
    float v[D];
    #pragma unroll
    for (int d = 0; d < D; ++d) v[d] = s_arr[row * D + d];
    float mx = v[0];
    #pragma unroll
    for (int d = 1; d < D; ++d) mx = fmaxf(mx, v[d]);
    float s = 0.f;
    float e[D];
    #pragma unroll
    for (int d = 0; d < D; ++d) { e[d] = __expf(TAU * (v[d] - mx)); s += e[d]; }
    float isv = 1.0f / s;
    #pragma unroll
    for (int d = 0; d < D; ++d)
      out[(size_t)(b0 + row) * D + d] = e[d] * isv;
  }
}

extern "C" void kernel_launch(void* const* d_in, const int* in_sizes, int n_in,
                              void* d_out, int out_size, void* d_ws, size_t ws_size,
                              hipStream_t stream) {
  const float* feat = (const float*)d_in[0];
  // d_in[1] = category (unused by forward math)
  const float* Wt  = (const float*)d_in[2];
  const float* Wd  = (const float*)d_in[3];
  const float* mem = (const float*)d_in[4];
  float* outp = (float*)d_out;
  float* PR   = (float*)d_ws;  // [192][768] f32 = 576 KiB

  precompute_pr<<<192, 256, 0, stream>>>(Wt, Wd, mem, PR);
  const int B = in_sizes[1];          // 32768 rows (category is [B])
  fused_kernel<<<B / BM, 256, 0, stream>>>(feat, PR, outp);
}

// Round 2
// 75.148 us; speedup vs baseline: 2.7702x; 2.7702x over previous
//
#include <hip/hip_runtime.h>
#include <math.h>

typedef __attribute__((ext_vector_type(8))) short short8;
typedef __attribute__((ext_vector_type(4))) float f32x4;
typedef __attribute__((ext_vector_type(4))) unsigned short u16x4;

#define TAUF 32.0f

constexpr int NT     = 24;      // K tiles: 768 / 32
constexpr int BUF_SZ = 40960;   // one LDS double-buffer half
constexpr int A_HI   = 0;       // 128 rows x 32 k x bf16 = 8192 B
constexpr int A_LO   = 8192;
constexpr int B_HI   = 16384;   // 192 rows x 32 k x bf16 = 12288 B
constexpr int B_LO   = 28672;
constexpr int CSTR   = 196;     // epilogue C row stride (floats)

// ---------------------------------------------------------------------------
// Kernel 1: PR[blk] = memory[dm] . W  (blk<90: W_topic ; 90..179: W_domain),
// emitted as split-bf16 planes PRhi/PRlo [192][768]; rows 180..191 zeroed.
// ---------------------------------------------------------------------------
__global__ __launch_bounds__(256) void precompute_pr(
    const float* __restrict__ Wt, const float* __restrict__ Wd,
    const float* __restrict__ mem, unsigned short* __restrict__ PRhi,
    unsigned short* __restrict__ PRlo) {
  int blk = blockIdx.x, t = threadIdx.x;
  if (blk >= 180) {
    for (int p = 0; p < 3; ++p) {
      PRhi[blk * 768 + t + p * 256] = 0;
      PRlo[blk * 768 + t + p * 256] = 0;
    }
    return;
  }
  __shared__ float mlds[256];
  const float* W = (blk >= 90) ? Wd : Wt;
  int dm = (blk >= 90) ? blk - 90 : blk;
  mlds[t] = mem[dm * 256 + t];
  __syncthreads();
  for (int p = 0; p < 3; ++p) {
    int i = t + p * 256;
    float acc = 0.f;
    #pragma unroll 8
    for (int e = 0; e < 256; ++e) acc += mlds[e] * W[e * 768 + i];
    unsigned int b = __float_as_uint(acc);
    unsigned short hi = (unsigned short)(b >> 16);
    float hf = __uint_as_float(b & 0xffff0000u);
    unsigned short lo = (unsigned short)(__float_as_uint(acc - hf) >> 16);
    PRhi[blk * 768 + i] = hi;
    PRlo[blk * 768 + i] = lo;
  }
}

// ---------------------------------------------------------------------------
// Kernel 2: fused split-bf16 MFMA GEMM [128 rows x 192 cols x K=768] +
// row L2-norm + double softmax. 512 threads = 8 waves; wave = (rowgroup rg,
// colgroup cg): 32 rows (2 MFMA rowtiles) x 96 cols (6 coltiles).
// ---------------------------------------------------------------------------
__global__ __launch_bounds__(512, 1) void fused_mfma(
    const float* __restrict__ feat, const unsigned short* __restrict__ PRhi,
    const unsigned short* __restrict__ PRlo, float* __restrict__ out) {
  __shared__ f32x4 smemv[6400];   // 102400 B: 2x40960 buffers, reused for C
  __shared__ float invn[128];
  __shared__ float sarr[1152];
  char* smem = (char*)smemv;

  const int t    = threadIdx.x;
  const int lane = t & 63;
  const int wid  = t >> 6;        // 0..7
  const int rg   = wid >> 1;      // 0..3
  const int cg   = wid & 1;       // 0..1
  const int b0   = blockIdx.x * 128;

  // ---- A staging map: slot t -> (row t>>3, quad t&7); slot t+512 -> row+64
  const int ar0 = t >> 3;
  const int aq  = t & 7;
  const float* gA0 = feat + (size_t)(b0 + ar0) * 768 + aq * 4;
  const float* gA1 = gA0 + (size_t)64 * 768;
  const int aw0 = ar0 * 64 + aq * 8;          // byte offset in A plane
  const int aw1 = (ar0 + 64) * 64 + aq * 8;

  // ---- B DMA map: 24 wave-instrs per ktile; wave wid issues ids wid*3..+2
  const int iid = wid * 3;

  // ---- MFMA fragment lane offset: row (lane&15), k-granule (lane>>4)*16B
  const int laneA = ((lane & 15) << 6) | ((lane >> 4) << 4);

  f32x4 acc0[6], acc1[6];
  #pragma unroll
  for (int j = 0; j < 6; ++j) {
    acc0[j] = (f32x4){0.f, 0.f, 0.f, 0.f};
    acc1[j] = (f32x4){0.f, 0.f, 0.f, 0.f};
  }
  float ssq0 = 0.f, ssq1 = 0.f;

  auto issueB = [&](int kt, int bb) {
    #pragma unroll
    for (int u = 0; u < 3; ++u) {
      int i  = iid + u;
      int pl = i / 12;           // 0: hi plane, 1: lo plane (wave-uniform)
      int idx = i - pl * 12;
      int G  = idx * 64 + lane;  // linear 16B granule: row G>>2, quad G&3
      const unsigned short* basep = pl ? PRlo : PRhi;
      const char* g = (const char*)basep + (G >> 2) * 1536 + kt * 64 + (G & 3) * 16;
      char* l = smem + bb * BUF_SZ + (pl ? B_LO : B_HI) + idx * 1024;  // uniform
      __builtin_amdgcn_global_load_lds((const unsigned int*)g, (unsigned int*)l,
                                       16, 0, 0);
    }
  };

  auto cvtwrite = [&](float4 v, char* dhi, char* dlo, float& ssq) {
    ssq += v.x * v.x + v.y * v.y + v.z * v.z + v.w * v.w;
    float xs[4] = {v.x, v.y, v.z, v.w};
    u16x4 hi, lo;
    #pragma unroll
    for (int e = 0; e < 4; ++e) {
      float x = xs[e];
      unsigned int bu = __float_as_uint(x);
      hi[e] = (unsigned short)(bu >> 16);
      float hf = __uint_as_float(bu & 0xffff0000u);
      lo[e] = (unsigned short)(__float_as_uint(x - hf) >> 16);
    }
    *(u16x4*)dhi = hi;
    *(u16x4*)dlo = lo;
  };

  auto domfma = [&](int bb) {
    char* base = smem + bb * BUF_SZ;
    const int aoff = rg * 2048 + laneA;
    short8 ah0 = *(const short8*)(base + A_HI + aoff);
    short8 ah1 = *(const short8*)(base + A_HI + aoff + 1024);
    short8 al0 = *(const short8*)(base + A_LO + aoff);
    short8 al1 = *(const short8*)(base + A_LO + aoff + 1024);
    const int boff = cg * 6144 + laneA;
    #pragma unroll
    for (int j = 0; j < 6; ++j) {
      short8 bh = *(const short8*)(base + B_HI + boff + j * 1024);
      short8 bl = *(const short8*)(base + B_LO + boff + j * 1024);
      acc0[j] = __builtin_amdgcn_mfma_f32_16x16x32_bf16(ah0, bh, acc0[j], 0, 0, 0);
      acc0[j] = __builtin_amdgcn_mfma_f32_16x16x32_bf16(al0, bh, acc0[j], 0, 0, 0);
      acc0[j] = __builtin_amdgcn_mfma_f32_16x16x32_bf16(ah0, bl, acc0[j], 0, 0, 0);
      acc1[j] = __builtin_amdgcn_mfma_f32_16x16x32_bf16(ah1, bh, acc1[j], 0, 0, 0);
      acc1[j] = __builtin_amdgcn_mfma_f32_16x16x32_bf16(al1, bh, acc1[j], 0, 0, 0);
      acc1[j] = __builtin_amdgcn_mfma_f32_16x16x32_bf16(ah1, bl, acc1[j], 0, 0, 0);
    }
  };

  // ---- prologue: stage kt=0 into buf0, prefetch A(1)
  float4 sa0 = *(const float4*)gA0;
  float4 sa1 = *(const float4*)gA1;
  issueB(0, 0);
  cvtwrite(sa0, smem + A_HI + aw0, smem + A_LO + aw0, ssq0);
  cvtwrite(sa1, smem + A_HI + aw1, smem + A_LO + aw1, ssq1);
  float4 sb0 = *(const float4*)(gA0 + 32);
  float4 sb1 = *(const float4*)(gA1 + 32);
  __syncthreads();

  // ---- main loop, unrolled x2 for compile-time reg-set parity
  for (int kp = 0; kp < 11; ++kp) {
    int kt = 2 * kp;
    // body(kt): stage kt+1 -> buf1, prefetch A(kt+2), compute buf0
    issueB(kt + 1, 1);
    cvtwrite(sb0, smem + BUF_SZ + A_HI + aw0, smem + BUF_SZ + A_LO + aw0, ssq0);
    cvtwrite(sb1, smem + BUF_SZ + A_HI + aw1, smem + BUF_SZ + A_LO + aw1, ssq1);
    sa0 = *(const float4*)(gA0 + (kt + 2) * 32);
    sa1 = *(const float4*)(gA1 + (kt + 2) * 32);
    domfma(0);
    __syncthreads();
    // body(kt+1): stage kt+2 -> buf0, prefetch A(kt+3), compute buf1
    issueB(kt + 2, 0);
    cvtwrite(sa0, smem + A_HI + aw0, smem + A_LO + aw0, ssq0);
    cvtwrite(sa1, smem + A_HI + aw1, smem + A_LO + aw1, ssq1);
    sb0 = *(const float4*)(gA0 + (kt + 3) * 32);
    sb1 = *(const float4*)(gA1 + (kt + 3) * 32);
    domfma(1);
    __syncthreads();
  }
  // kt=22: stage kt=23 -> buf1 (A(23) is in set sb), compute buf0
  issueB(23, 1);
  cvtwrite(sb0, smem + BUF_SZ + A_HI + aw0, smem + BUF_SZ + A_LO + aw0, ssq0);
  cvtwrite(sb1, smem + BUF_SZ + A_HI + aw1, smem + BUF_SZ + A_LO + aw1, ssq1);
  domfma(0);
  __syncthreads();
  // kt=23: compute buf1
  domfma(1);

  // ---- row L2-norm: reduce ssq over the 8 lanes sharing a row
  float s0 = ssq0, s1 = ssq1;
  #pragma unroll
  for (int m = 1; m <= 4; m <<= 1) {
    s0 += __shfl_xor(s0, m, 64);
    s1 += __shfl_xor(s1, m, 64);
  }
  if ((t & 7) == 0) {
    invn[ar0]      = rsqrtf(s0);
    invn[ar0 + 64] = rsqrtf(s1);
  }
  __syncthreads();   // all MFMA reads done; invn visible; buffers reusable

  // ---- write scaled C (q|r) to LDS
  float* Clds = (float*)smem;
  #pragma unroll
  for (int rt = 0; rt < 2; ++rt) {
    int rbase = rg * 32 + rt * 16 + ((lane >> 4) << 2);
    #pragma unroll
    for (int j = 0; j < 6; ++j) {
      int col = (cg * 6 + j) * 16 + (lane & 15);
      f32x4 v = rt ? acc1[j] : acc0[j];
      #pragma unroll
      for (int jj = 0; jj < 4; ++jj)
        Clds[(rbase + jj) * CSTR + col] = v[jj] * invn[rbase + jj];
    }
  }
  __syncthreads();

  // ---- per (row,d): softmax over m, dot with r
  for (int pid = t; pid < 1152; pid += 512) {
    int row = pid / 9, d = pid - row * 9;
    const float* qp = Clds + row * CSTR + d * 10;
    const float* rp = qp + 90;
    float mx = qp[0];
    #pragma unroll
    for (int m = 1; m < 10; ++m) mx = fmaxf(mx, qp[m]);
    float s = 0.f, val = 0.f;
    #pragma unroll
    for (int m = 0; m < 10; ++m) {
      float e = __expf(TAUF * (qp[m] - mx));
      s += e;
      val += e * rp[m];
    }
    sarr[pid] = val / s;
  }
  __syncthreads();

  // ---- per row: softmax over d, write out
  if (t < 128) {
    float v[9];
    #pragma unroll
    for (int d = 0; d < 9; ++d) v[d] = sarr[t * 9 + d];
    float mx = v[0];
    #pragma unroll
    for (int d = 1; d < 9; ++d) mx = fmaxf(mx, v[d]);
    float s = 0.f;
    float e[9];
    #pragma unroll
    for (int d = 0; d < 9; ++d) {
      e[d] = __expf(TAUF * (v[d] - mx));
      s += e[d];
    }
    float is = 1.f / s;
    #pragma unroll
    for (int d = 0; d < 9; ++d)
      out[(size_t)(b0 + t) * 9 + d] = e[d] * is;
  }
}

extern "C" void kernel_launch(void* const* d_in, const int* in_sizes, int n_in,
                              void* d_out, int out_size, void* d_ws, size_t ws_size,
                              hipStream_t stream) {
  const float* feat = (const float*)d_in[0];
  // d_in[1] = category (unused by forward math)
  const float* Wt  = (const float*)d_in[2];
  const float* Wd  = (const float*)d_in[3];
  const float* mem = (const float*)d_in[4];
  float* outp = (float*)d_out;

  unsigned short* PRhi = (unsigned short*)d_ws;            // [192][768] bf16
  unsigned short* PRlo = PRhi + 192 * 768;                 // [192][768] bf16
  // total ws use: 2 * 192*768*2 B = 589824 B (same as round-1 footprint)

  precompute_pr<<<192, 256, 0, stream>>>(Wt, Wd, mem, PRhi, PRlo);
  const int B = in_sizes[1];   // 32768
  fused_mfma<<<B / 128, 512, 0, stream>>>(feat, PRhi, PRlo, outp);
}